// Round 1
// baseline (1451.124 us; speedup 1.0000x reference)
//
#include <hip/hip_runtime.h>
#include <stdint.h>

typedef short bfrag __attribute__((ext_vector_type(8)));   // 8 bf16 (4 VGPR)
typedef float facc4 __attribute__((ext_vector_type(4)));   // MFMA accumulator

__device__ __forceinline__ unsigned short f2bf(float x){
  union { float f; uint32_t u; } v; v.f = x;
  uint32_t r = v.u + 0x7FFFu + ((v.u >> 16) & 1u);   // RNE
  return (unsigned short)(r >> 16);
}
__device__ __forceinline__ float bf2f(unsigned short h){
  union { uint32_t u; float f; } v; v.u = ((uint32_t)h) << 16; return v.f;
}
__device__ __forceinline__ uint32_t pack2(unsigned short a, unsigned short b){
  return (uint32_t)a | ((uint32_t)b << 16);
}

// ---------------------------------------------------------------------------
// Unified tiled GEMM.
// AMODE: 0 = A is f32, split to hi/lo inline (3-pass). 1 = A is pre-split bf16
//        pair (hi at A0, lo at A1), 3-pass. 2 = plain bf16 (1-pass, BK=64).
// CMODE: 0 = f32 output (ldc). 1 = qw split-interleaved ushort rows
//        [hi(1024)|lo(1024)] written to C (ldc fixed 2048).
// LDS rows are 128 B: SPLIT -> [hi k0..k31 | lo k0..k31], PLAIN -> 64 bf16.
// XOR swizzle on 16B slots: off = row*128 + ((slot*16) ^ ((row&7)<<4)).
// ---------------------------------------------------------------------------
template<int AMODE, int BM, int BN, int NW, int CMODE>
__global__ __launch_bounds__(NW*64, 2)
void gemm_kernel(const void* __restrict__ A0, const void* __restrict__ A1,
                 const unsigned short* __restrict__ B0,
                 const unsigned short* __restrict__ B1,
                 void* __restrict__ C,
                 int lda, int ldb, int ldc, int K,
                 long abstr, long bbstr, long cbstr)
{
  constexpr bool SPLIT = (AMODE <= 1);
  constexpr int  BK    = SPLIT ? 32 : 64;
  constexpr int  NT    = NW * 64;
  constexpr int  NWN   = BN / 64;
  constexpr int  NWM   = BM / 64;
  static_assert(NWM * NWN == NW, "wave grid");
  constexpr int  BUF   = (BM + BN) * 128;
  constexpr int  BCPT  = BN * 8 / NT;                       // B 16B-chunks/thread
  constexpr int  ACPT  = (AMODE == 0) ? (BM * 4 / NT) : (BM * 8 / NT);
  constexpr int  AREG  = (AMODE == 0) ? 2 * ACPT : ACPT;

  __shared__ __align__(16) char smem[2 * BUF];

  const int tid = threadIdx.x;
  const int z   = blockIdx.z;
  const int m0  = blockIdx.x * BM;
  const int n0  = blockIdx.y * BN;

  const float* Af = nullptr;
  const unsigned short* Ahi = nullptr;
  const unsigned short* Alo = nullptr;
  if constexpr (AMODE == 0) {
    Af = (const float*)A0 + (size_t)z * (size_t)abstr;
  } else {
    Ahi = (const unsigned short*)A0 + (size_t)z * (size_t)abstr;
    if constexpr (AMODE == 1)
      Alo = (const unsigned short*)A1 + (size_t)z * (size_t)abstr;
  }
  const unsigned short* Bhi = B0 + (size_t)z * (size_t)bbstr;
  const unsigned short* Blo = nullptr;
  if constexpr (SPLIT) Blo = B1 + (size_t)z * (size_t)bbstr;

  uint4 areg[AREG];
  uint4 breg[BCPT];

  auto stage_load = [&](int kt){
    const int k0 = kt * BK;
    #pragma unroll
    for (int i = 0; i < BCPT; ++i){
      int ci = i * NT + tid;
      int row = ci >> 3, slot = ci & 7;
      const unsigned short* src; int kk;
      if constexpr (SPLIT) { src = (slot < 4) ? Bhi : Blo; kk = (slot & 3) * 8; }
      else                 { src = Bhi;                    kk = slot * 8; }
      breg[i] = *(const uint4*)(src + (size_t)(n0 + row) * ldb + k0 + kk);
    }
    if constexpr (AMODE == 0) {
      #pragma unroll
      for (int i = 0; i < ACPT; ++i){
        int ci = i * NT + tid;
        int row = ci >> 2, s = ci & 3;
        const float* src = Af + (size_t)(m0 + row) * lda + k0 + s * 8;
        areg[2*i]   = *(const uint4*)(src);
        areg[2*i+1] = *(const uint4*)(src + 4);
      }
    } else {
      #pragma unroll
      for (int i = 0; i < ACPT; ++i){
        int ci = i * NT + tid;
        int row = ci >> 3, slot = ci & 7;
        const unsigned short* src; int kk;
        if constexpr (SPLIT) { src = (slot < 4) ? Ahi : Alo; kk = (slot & 3) * 8; }
        else                 { src = Ahi;                    kk = slot * 8; }
        areg[i] = *(const uint4*)(src + (size_t)(m0 + row) * lda + k0 + kk);
      }
    }
  };

  auto stage_store = [&](int buf){
    char* la = smem + buf * BUF;
    char* lb = la + BM * 128;
    #pragma unroll
    for (int i = 0; i < BCPT; ++i){
      int ci = i * NT + tid;
      int row = ci >> 3, slot = ci & 7;
      int off = row * 128 + ((slot * 16) ^ ((row & 7) << 4));
      *(uint4*)(lb + off) = breg[i];
    }
    if constexpr (AMODE == 0) {
      #pragma unroll
      for (int i = 0; i < ACPT; ++i){
        int ci = i * NT + tid;
        int row = ci >> 2, s = ci & 3;
        const float* f0 = (const float*)&areg[2*i];
        const float* f1 = (const float*)&areg[2*i+1];
        unsigned short h[8], l[8];
        #pragma unroll
        for (int j = 0; j < 4; ++j){
          float v0 = f0[j], v1 = f1[j];
          h[j]   = f2bf(v0); l[j]   = f2bf(v0 - bf2f(h[j]));
          h[4+j] = f2bf(v1); l[4+j] = f2bf(v1 - bf2f(h[4+j]));
        }
        uint4 hv, lv;
        hv.x = pack2(h[0],h[1]); hv.y = pack2(h[2],h[3]);
        hv.z = pack2(h[4],h[5]); hv.w = pack2(h[6],h[7]);
        lv.x = pack2(l[0],l[1]); lv.y = pack2(l[2],l[3]);
        lv.z = pack2(l[4],l[5]); lv.w = pack2(l[6],l[7]);
        int offh = row * 128 + ((s * 16)       ^ ((row & 7) << 4));
        int offl = row * 128 + (((s + 4) * 16) ^ ((row & 7) << 4));
        *(uint4*)(la + offh) = hv;
        *(uint4*)(la + offl) = lv;
      }
    } else {
      #pragma unroll
      for (int i = 0; i < ACPT; ++i){
        int ci = i * NT + tid;
        int row = ci >> 3, slot = ci & 7;
        int off = row * 128 + ((slot * 16) ^ ((row & 7) << 4));
        *(uint4*)(la + off) = areg[i];
      }
    }
  };

  const int lane = tid & 63;
  const int wv = tid >> 6;
  const int wm = wv / NWN, wn = wv % NWN;
  const int fr = lane & 15;
  const int fk = lane >> 4;     // 0..3

  facc4 acc[4][4];
  #pragma unroll
  for (int a = 0; a < 4; ++a)
    #pragma unroll
    for (int b = 0; b < 4; ++b)
      acc[a][b] = (facc4){0.f, 0.f, 0.f, 0.f};

  auto compute = [&](int buf){
    const char* la = smem + buf * BUF;
    const char* lb = la + BM * 128;
    #pragma unroll
    for (int kk = 0; kk < (SPLIT ? 1 : 2); ++kk){
      bfrag ah[4], al[4], bh[4], bl[4];
      #pragma unroll
      for (int mi = 0; mi < 4; ++mi){
        int row = wm*64 + mi*16 + fr;
        int sh = SPLIT ? fk : (kk*4 + fk);
        ah[mi] = *(const bfrag*)(la + row*128 + ((sh*16) ^ ((row&7)<<4)));
        if constexpr (SPLIT)
          al[mi] = *(const bfrag*)(la + row*128 + (((fk+4)*16) ^ ((row&7)<<4)));
      }
      #pragma unroll
      for (int ni = 0; ni < 4; ++ni){
        int row = wn*64 + ni*16 + fr;
        int sh = SPLIT ? fk : (kk*4 + fk);
        bh[ni] = *(const bfrag*)(lb + row*128 + ((sh*16) ^ ((row&7)<<4)));
        if constexpr (SPLIT)
          bl[ni] = *(const bfrag*)(lb + row*128 + (((fk+4)*16) ^ ((row&7)<<4)));
      }
      #pragma unroll
      for (int mi = 0; mi < 4; ++mi)
        #pragma unroll
        for (int ni = 0; ni < 4; ++ni){
          acc[mi][ni] = __builtin_amdgcn_mfma_f32_16x16x32_bf16(ah[mi], bh[ni], acc[mi][ni], 0, 0, 0);
          if constexpr (SPLIT){
            acc[mi][ni] = __builtin_amdgcn_mfma_f32_16x16x32_bf16(ah[mi], bl[ni], acc[mi][ni], 0, 0, 0);
            acc[mi][ni] = __builtin_amdgcn_mfma_f32_16x16x32_bf16(al[mi], bh[ni], acc[mi][ni], 0, 0, 0);
          }
        }
    }
  };

  const int NTILES = K / BK;
  stage_load(0);
  stage_store(0);
  __syncthreads();
  for (int kt = 0; kt < NTILES; ++kt){
    int cur = kt & 1;
    if (kt + 1 < NTILES) stage_load(kt + 1);
    compute(cur);
    if (kt + 1 < NTILES) stage_store(cur ^ 1);
    __syncthreads();
  }

  #pragma unroll
  for (int mi = 0; mi < 4; ++mi)
    #pragma unroll
    for (int ni = 0; ni < 4; ++ni)
      #pragma unroll
      for (int j = 0; j < 4; ++j){
        int row = m0 + wm*64 + mi*16 + (lane >> 4)*4 + j;
        int col = n0 + wn*64 + ni*16 + (lane & 15);
        float v = acc[mi][ni][j];
        if constexpr (CMODE == 0){
          ((float*)C)[(size_t)z * (size_t)cbstr + (size_t)row * ldc + col] = v;
        } else {
          unsigned short* o = (unsigned short*)C;
          unsigned short h = f2bf(v);
          o[(size_t)row * 2048 + col]        = h;
          o[(size_t)row * 2048 + 1024 + col] = f2bf(v - bf2f(h));
        }
      }
}

// W[e][n] f32  ->  Wt_hi/Wt_lo[n][e] bf16 split
__global__ __launch_bounds__(256)
void wt_kernel(const float* __restrict__ W, unsigned short* __restrict__ Whi,
               unsigned short* __restrict__ Wlo)
{
  __shared__ float tile[64][65];
  const int e0 = blockIdx.x * 64, n0 = blockIdx.y * 64;
  const int t = threadIdx.x;
  const int r = t >> 2, cq = t & 3;
  #pragma unroll
  for (int i = 0; i < 4; ++i){
    float4 f = *(const float4*)(W + (size_t)(e0 + r) * 1024 + n0 + cq*16 + i*4);
    tile[r][cq*16 + i*4 + 0] = f.x;
    tile[r][cq*16 + i*4 + 1] = f.y;
    tile[r][cq*16 + i*4 + 2] = f.z;
    tile[r][cq*16 + i*4 + 3] = f.w;
  }
  __syncthreads();
  unsigned short h[16], l[16];
  #pragma unroll
  for (int i = 0; i < 16; ++i){
    float v = tile[cq*16 + i][r];
    h[i] = f2bf(v);
    l[i] = f2bf(v - bf2f(h[i]));
  }
  uint4 ha, hb, la4, lb4;
  ha.x=pack2(h[0],h[1]);   ha.y=pack2(h[2],h[3]);   ha.z=pack2(h[4],h[5]);   ha.w=pack2(h[6],h[7]);
  hb.x=pack2(h[8],h[9]);   hb.y=pack2(h[10],h[11]); hb.z=pack2(h[12],h[13]); hb.w=pack2(h[14],h[15]);
  la4.x=pack2(l[0],l[1]);  la4.y=pack2(l[2],l[3]);  la4.z=pack2(l[4],l[5]);  la4.w=pack2(l[6],l[7]);
  lb4.x=pack2(l[8],l[9]);  lb4.y=pack2(l[10],l[11]);lb4.z=pack2(l[12],l[13]);lb4.w=pack2(l[14],l[15]);
  size_t o = (size_t)(n0 + r) * 1024 + e0 + cq*16;
  *(uint4*)(Whi + o)     = ha;
  *(uint4*)(Whi + o + 8) = hb;
  *(uint4*)(Wlo + o)     = la4;
  *(uint4*)(Wlo + o + 8) = lb4;
}

// k[b][kv][e] f32 -> khi/klo[b][kv][e] bf16 and kT[b][e][kv] bf16 (hi only)
__global__ __launch_bounds__(256)
void prep_kernel(const float* __restrict__ kin, unsigned short* __restrict__ khi,
                 unsigned short* __restrict__ klo, unsigned short* __restrict__ kT)
{
  __shared__ float tile[64][65];
  const int bz = blockIdx.z;
  const float* kb = kin + (size_t)bz * 2048 * 1024;
  unsigned short* khib = khi + (size_t)bz * 2048 * 1024;
  unsigned short* klob = klo + (size_t)bz * 2048 * 1024;
  unsigned short* kTb  = kT  + (size_t)bz * 1024 * 2048;
  const int kv0 = blockIdx.x * 64, e0 = blockIdx.y * 64;
  const int t = threadIdx.x;
  const int r = t >> 2, cq = t & 3;
  #pragma unroll
  for (int i = 0; i < 4; ++i){
    float4 f = *(const float4*)(kb + (size_t)(kv0 + r) * 1024 + e0 + cq*16 + i*4);
    unsigned short h0=f2bf(f.x), h1=f2bf(f.y), h2=f2bf(f.z), h3=f2bf(f.w);
    uint2 hv, lv;
    hv.x = pack2(h0, h1); hv.y = pack2(h2, h3);
    lv.x = pack2(f2bf(f.x - bf2f(h0)), f2bf(f.y - bf2f(h1)));
    lv.y = pack2(f2bf(f.z - bf2f(h2)), f2bf(f.w - bf2f(h3)));
    size_t o = (size_t)(kv0 + r) * 1024 + e0 + cq*16 + i*4;
    *(uint2*)(khib + o) = hv;
    *(uint2*)(klob + o) = lv;
    tile[r][cq*16 + i*4 + 0] = f.x;
    tile[r][cq*16 + i*4 + 1] = f.y;
    tile[r][cq*16 + i*4 + 2] = f.z;
    tile[r][cq*16 + i*4 + 3] = f.w;
  }
  __syncthreads();
  unsigned short h[16];
  #pragma unroll
  for (int i = 0; i < 16; ++i) h[i] = f2bf(tile[cq*16 + i][r]);
  uint4 va, vb;
  va.x=pack2(h[0],h[1]);  va.y=pack2(h[2],h[3]);   va.z=pack2(h[4],h[5]);   va.w=pack2(h[6],h[7]);
  vb.x=pack2(h[8],h[9]);  vb.y=pack2(h[10],h[11]); vb.z=pack2(h[12],h[13]); vb.w=pack2(h[14],h[15]);
  size_t o = (size_t)(e0 + r) * 2048 + kv0 + cq*16;
  *(uint4*)(kTb + o)     = va;
  *(uint4*)(kTb + o + 8) = vb;
}

// exact row softmax over 2048 f32, then * mask, -> bf16
__global__ __launch_bounds__(256)
void softmax_kernel(const float* __restrict__ S, const int* __restrict__ mask,
                    unsigned short* __restrict__ P)
{
  const int row = blockIdx.x;
  const float* s = S + (size_t)row * 2048;
  const int* mk = mask + (size_t)row * 2048;
  unsigned short* p = P + (size_t)row * 2048;
  const int t = threadIdx.x;
  float4 v0 = ((const float4*)s)[t];
  float4 v1 = ((const float4*)s)[t + 256];
  float m = fmaxf(fmaxf(fmaxf(v0.x, v0.y), fmaxf(v0.z, v0.w)),
                  fmaxf(fmaxf(v1.x, v1.y), fmaxf(v1.z, v1.w)));
  #pragma unroll
  for (int off = 32; off > 0; off >>= 1) m = fmaxf(m, __shfl_xor(m, off));
  __shared__ float rmax[4], rsum[4];
  const int wid = t >> 6;
  if ((t & 63) == 0) rmax[wid] = m;
  __syncthreads();
  m = fmaxf(fmaxf(rmax[0], rmax[1]), fmaxf(rmax[2], rmax[3]));
  float e0 = __expf(v0.x - m), e1 = __expf(v0.y - m), e2 = __expf(v0.z - m), e3 = __expf(v0.w - m);
  float e4 = __expf(v1.x - m), e5 = __expf(v1.y - m), e6 = __expf(v1.z - m), e7 = __expf(v1.w - m);
  float ssum = ((e0 + e1) + (e2 + e3)) + ((e4 + e5) + (e6 + e7));
  #pragma unroll
  for (int off = 32; off > 0; off >>= 1) ssum += __shfl_xor(ssum, off);
  if ((t & 63) == 0) rsum[wid] = ssum;
  __syncthreads();
  float inv = 1.f / (rsum[0] + rsum[1] + rsum[2] + rsum[3]);
  int4 m0 = ((const int4*)mk)[t];
  int4 m1 = ((const int4*)mk)[t + 256];
  ushort4 o0, o1;
  o0.x = f2bf(e0 * inv * (float)m0.x);
  o0.y = f2bf(e1 * inv * (float)m0.y);
  o0.z = f2bf(e2 * inv * (float)m0.z);
  o0.w = f2bf(e3 * inv * (float)m0.w);
  o1.x = f2bf(e4 * inv * (float)m1.x);
  o1.y = f2bf(e5 * inv * (float)m1.y);
  o1.z = f2bf(e6 * inv * (float)m1.z);
  o1.w = f2bf(e7 * inv * (float)m1.w);
  ((ushort4*)p)[t]       = o0;
  ((ushort4*)p)[t + 256] = o1;
}

extern "C" void kernel_launch(void* const* d_in, const int* in_sizes, int n_in,
                              void* d_out, int out_size, void* d_ws, size_t ws_size,
                              hipStream_t stream)
{
  (void)in_sizes; (void)n_in; (void)out_size;
  const float* kin  = (const float*)d_in[0];
  const float* qin  = (const float*)d_in[1];
  const float* Win  = (const float*)d_in[2];
  const int*   mask = (const int*)d_in[3];

  // ws layout: Wt_hi (2MB) | Wt_lo (2MB) | per-chunk { khi | klo | kT | S | P }
  unsigned short* Wt_hi = (unsigned short*)d_ws;
  unsigned short* Wt_lo = Wt_hi + 1024 * 1024;
  char* cbase = (char*)d_ws + (4ll << 20);

  int bpc = 1;  // batches per chunk (36 MB each + 4 MB fixed)
  {
    const size_t per_b = (size_t)2048*1024*2*2 + (size_t)1024*2048*2
                       + (size_t)2048*2048*4 + (size_t)2048*2048*2;
    const int cands[5] = {16, 8, 4, 2, 1};
    for (int i = 0; i < 5; ++i){
      size_t need = (4ull << 20) + (size_t)cands[i] * per_b;
      if (need <= ws_size){ bpc = cands[i]; break; }
    }
  }
  unsigned short* khi = (unsigned short*)cbase;
  unsigned short* klo = khi + (size_t)bpc * 2048 * 1024;
  unsigned short* kT  = klo + (size_t)bpc * 2048 * 1024;
  float*          Sb  = (float*)(kT + (size_t)bpc * 1024 * 2048);
  unsigned short* Pb  = (unsigned short*)(Sb + (size_t)bpc * 2048 * 2048);

  // K0: W transpose+split
  wt_kernel<<<dim3(16, 16, 1), 256, 0, stream>>>(Win, Wt_hi, Wt_lo);

  // K1: qw = q @ W  (f32-split 3-pass), -> d_out as interleaved hi|lo bf16 rows
  gemm_kernel<0, 128, 256, 8, 1><<<dim3(32768/128, 1024/256, 1), 512, 0, stream>>>(
      qin, nullptr, Wt_hi, Wt_lo, d_out,
      1024, 1024, 0, 1024, 0, 0, 0);

  for (int cb = 0; cb < 16; cb += bpc){
    prep_kernel<<<dim3(32, 16, bpc), 256, 0, stream>>>(
        kin + (size_t)cb * 2048 * 1024, khi, klo, kT);

    // K2: S = qw @ k^T (pre-split bf16 3-pass), batched
    const unsigned short* qw = (const unsigned short*)d_out + (size_t)cb * 2048 * 2048;
    gemm_kernel<1, 128, 256, 8, 0><<<dim3(2048/128, 2048/256, bpc), 512, 0, stream>>>(
        qw, qw + 1024, khi, klo, Sb,
        2048, 1024, 2048, 1024,
        (long)2048 * 2048, (long)2048 * 1024, (long)2048 * 2048);

    // K3: row softmax * mask -> P (bf16)
    softmax_kernel<<<dim3(bpc * 2048, 1, 1), 256, 0, stream>>>(
        Sb, mask + (size_t)cb * 2048 * 2048, Pb);

    // K4: O = P @ k (plain bf16), overwrites this chunk's qw rows in d_out
    gemm_kernel<2, 128, 128, 4, 0><<<dim3(2048/128, 1024/128, bpc), 256, 0, stream>>>(
        Pb, nullptr, kT, nullptr, (float*)d_out + (size_t)cb * 2048 * 1024,
        2048, 2048, 1024, 2048,
        (long)2048 * 2048, (long)1024 * 2048, (long)2048 * 1024);
  }
}

// Round 2
// 1448.111 us; speedup vs baseline: 1.0021x; 1.0021x over previous
//
#include <hip/hip_runtime.h>
#include <stdint.h>

typedef short bfrag __attribute__((ext_vector_type(8)));   // 8 bf16 (4 VGPR)
typedef float facc4 __attribute__((ext_vector_type(4)));   // MFMA accumulator

__device__ __forceinline__ unsigned short f2bf(float x){
  union { float f; uint32_t u; } v; v.f = x;
  uint32_t r = v.u + 0x7FFFu + ((v.u >> 16) & 1u);   // RNE
  return (unsigned short)(r >> 16);
}
__device__ __forceinline__ float bf2f(unsigned short h){
  union { uint32_t u; float f; } v; v.u = ((uint32_t)h) << 16; return v.f;
}
__device__ __forceinline__ uint32_t pack2(unsigned short a, unsigned short b){
  return (uint32_t)a | ((uint32_t)b << 16);
}

// ---------------------------------------------------------------------------
// Unified tiled GEMM.
// AMODE: 0 = A is f32, split to hi/lo inline (3-pass). 1 = A is pre-split bf16
//        pair (hi at A0, lo at A1), 3-pass. 2 = plain bf16 (1-pass, BK=64).
// CMODE: 0 = f32 output (ldc). 1 = qw split-interleaved ushort rows
//        [hi(1024)|lo(1024)] written to C (ldc fixed 2048).
// LDS rows are 128 B: SPLIT -> [hi k0..k31 | lo k0..k31], PLAIN -> 64 bf16.
// XOR swizzle on 16B slots: off = row*128 + ((slot*16) ^ ((row&7)<<4)).
// ---------------------------------------------------------------------------
template<int AMODE, int BM, int BN, int NW, int CMODE>
__global__ __launch_bounds__(NW*64, 2)
void gemm_kernel(const void* __restrict__ A0, const void* __restrict__ A1,
                 const unsigned short* __restrict__ B0,
                 const unsigned short* __restrict__ B1,
                 void* __restrict__ C,
                 int lda, int ldb, int ldc, int K,
                 long abstr, long bbstr, long cbstr)
{
  constexpr bool SPLIT = (AMODE <= 1);
  constexpr int  BK    = SPLIT ? 32 : 64;
  constexpr int  NT    = NW * 64;
  constexpr int  NWN   = BN / 64;
  constexpr int  NWM   = BM / 64;
  static_assert(NWM * NWN == NW, "wave grid");
  constexpr int  BUF   = (BM + BN) * 128;
  constexpr int  BCPT  = BN * 8 / NT;                       // B 16B-chunks/thread
  constexpr int  ACPT  = (AMODE == 0) ? (BM * 4 / NT) : (BM * 8 / NT);
  constexpr int  AREG  = (AMODE == 0) ? 2 * ACPT : ACPT;

  __shared__ __align__(16) char smem[2 * BUF];

  const int tid = threadIdx.x;
  const int z   = blockIdx.z;
  const int m0  = blockIdx.x * BM;
  const int n0  = blockIdx.y * BN;

  const float* Af = nullptr;
  const unsigned short* Ahi = nullptr;
  const unsigned short* Alo = nullptr;
  if constexpr (AMODE == 0) {
    Af = (const float*)A0 + (size_t)z * (size_t)abstr;
  } else {
    Ahi = (const unsigned short*)A0 + (size_t)z * (size_t)abstr;
    if constexpr (AMODE == 1)
      Alo = (const unsigned short*)A1 + (size_t)z * (size_t)abstr;
  }
  const unsigned short* Bhi = B0 + (size_t)z * (size_t)bbstr;
  const unsigned short* Blo = nullptr;
  if constexpr (SPLIT) Blo = B1 + (size_t)z * (size_t)bbstr;

  uint4 areg[AREG];
  uint4 breg[BCPT];

  auto stage_load = [&](int kt){
    const int k0 = kt * BK;
    #pragma unroll
    for (int i = 0; i < BCPT; ++i){
      int ci = i * NT + tid;
      int row = ci >> 3, slot = ci & 7;
      const unsigned short* src; int kk;
      if constexpr (SPLIT) { src = (slot < 4) ? Bhi : Blo; kk = (slot & 3) * 8; }
      else                 { src = Bhi;                    kk = slot * 8; }
      breg[i] = *(const uint4*)(src + (size_t)(n0 + row) * ldb + k0 + kk);
    }
    if constexpr (AMODE == 0) {
      #pragma unroll
      for (int i = 0; i < ACPT; ++i){
        int ci = i * NT + tid;
        int row = ci >> 2, s = ci & 3;
        const float* src = Af + (size_t)(m0 + row) * lda + k0 + s * 8;
        areg[2*i]   = *(const uint4*)(src);
        areg[2*i+1] = *(const uint4*)(src + 4);
      }
    } else {
      #pragma unroll
      for (int i = 0; i < ACPT; ++i){
        int ci = i * NT + tid;
        int row = ci >> 3, slot = ci & 7;
        const unsigned short* src; int kk;
        if constexpr (SPLIT) { src = (slot < 4) ? Ahi : Alo; kk = (slot & 3) * 8; }
        else                 { src = Ahi;                    kk = slot * 8; }
        areg[i] = *(const uint4*)(src + (size_t)(m0 + row) * lda + k0 + kk);
      }
    }
  };

  auto stage_store = [&](int buf){
    char* la = smem + buf * BUF;
    char* lb = la + BM * 128;
    #pragma unroll
    for (int i = 0; i < BCPT; ++i){
      int ci = i * NT + tid;
      int row = ci >> 3, slot = ci & 7;
      int off = row * 128 + ((slot * 16) ^ ((row & 7) << 4));
      *(uint4*)(lb + off) = breg[i];
    }
    if constexpr (AMODE == 0) {
      #pragma unroll
      for (int i = 0; i < ACPT; ++i){
        int ci = i * NT + tid;
        int row = ci >> 2, s = ci & 3;
        const float* f0 = (const float*)&areg[2*i];
        const float* f1 = (const float*)&areg[2*i+1];
        unsigned short h[8], l[8];
        #pragma unroll
        for (int j = 0; j < 4; ++j){
          float v0 = f0[j], v1 = f1[j];
          h[j]   = f2bf(v0); l[j]   = f2bf(v0 - bf2f(h[j]));
          h[4+j] = f2bf(v1); l[4+j] = f2bf(v1 - bf2f(h[4+j]));
        }
        uint4 hv, lv;
        hv.x = pack2(h[0],h[1]); hv.y = pack2(h[2],h[3]);
        hv.z = pack2(h[4],h[5]); hv.w = pack2(h[6],h[7]);
        lv.x = pack2(l[0],l[1]); lv.y = pack2(l[2],l[3]);
        lv.z = pack2(l[4],l[5]); lv.w = pack2(l[6],l[7]);
        int offh = row * 128 + ((s * 16)       ^ ((row & 7) << 4));
        int offl = row * 128 + (((s + 4) * 16) ^ ((row & 7) << 4));
        *(uint4*)(la + offh) = hv;
        *(uint4*)(la + offl) = lv;
      }
    } else {
      #pragma unroll
      for (int i = 0; i < ACPT; ++i){
        int ci = i * NT + tid;
        int row = ci >> 3, slot = ci & 7;
        int off = row * 128 + ((slot * 16) ^ ((row & 7) << 4));
        *(uint4*)(la + off) = areg[i];
      }
    }
  };

  const int lane = tid & 63;
  const int wv = tid >> 6;
  const int wm = wv / NWN, wn = wv % NWN;
  const int fr = lane & 15;
  const int fk = lane >> 4;     // 0..3

  facc4 acc[4][4];
  #pragma unroll
  for (int a = 0; a < 4; ++a)
    #pragma unroll
    for (int b = 0; b < 4; ++b)
      acc[a][b] = (facc4){0.f, 0.f, 0.f, 0.f};

  auto compute = [&](int buf){
    const char* la = smem + buf * BUF;
    const char* lb = la + BM * 128;
    #pragma unroll
    for (int kk = 0; kk < (SPLIT ? 1 : 2); ++kk){
      bfrag ah[4], al[4], bh[4], bl[4];
      #pragma unroll
      for (int mi = 0; mi < 4; ++mi){
        int row = wm*64 + mi*16 + fr;
        int sh = SPLIT ? fk : (kk*4 + fk);
        ah[mi] = *(const bfrag*)(la + row*128 + ((sh*16) ^ ((row&7)<<4)));
        if constexpr (SPLIT)
          al[mi] = *(const bfrag*)(la + row*128 + (((fk+4)*16) ^ ((row&7)<<4)));
      }
      #pragma unroll
      for (int ni = 0; ni < 4; ++ni){
        int row = wn*64 + ni*16 + fr;
        int sh = SPLIT ? fk : (kk*4 + fk);
        bh[ni] = *(const bfrag*)(lb + row*128 + ((sh*16) ^ ((row&7)<<4)));
        if constexpr (SPLIT)
          bl[ni] = *(const bfrag*)(lb + row*128 + (((fk+4)*16) ^ ((row&7)<<4)));
      }
      #pragma unroll
      for (int mi = 0; mi < 4; ++mi)
        #pragma unroll
        for (int ni = 0; ni < 4; ++ni){
          acc[mi][ni] = __builtin_amdgcn_mfma_f32_16x16x32_bf16(ah[mi], bh[ni], acc[mi][ni], 0, 0, 0);
          if constexpr (SPLIT){
            acc[mi][ni] = __builtin_amdgcn_mfma_f32_16x16x32_bf16(ah[mi], bl[ni], acc[mi][ni], 0, 0, 0);
            acc[mi][ni] = __builtin_amdgcn_mfma_f32_16x16x32_bf16(al[mi], bh[ni], acc[mi][ni], 0, 0, 0);
          }
        }
    }
  };

  const int NTILES = K / BK;
  stage_load(0);
  stage_store(0);
  __syncthreads();
  for (int kt = 0; kt < NTILES; ++kt){
    int cur = kt & 1;
    if (kt + 1 < NTILES) stage_load(kt + 1);
    compute(cur);
    if (kt + 1 < NTILES) stage_store(cur ^ 1);
    __syncthreads();
  }

  #pragma unroll
  for (int mi = 0; mi < 4; ++mi)
    #pragma unroll
    for (int ni = 0; ni < 4; ++ni)
      #pragma unroll
      for (int j = 0; j < 4; ++j){
        int row = m0 + wm*64 + mi*16 + (lane >> 4)*4 + j;
        int col = n0 + wn*64 + ni*16 + (lane & 15);
        float v = acc[mi][ni][j];
        if constexpr (CMODE == 0){
          ((float*)C)[(size_t)z * (size_t)cbstr + (size_t)row * ldc + col] = v;
        } else {
          unsigned short* o = (unsigned short*)C;
          unsigned short h = f2bf(v);
          o[(size_t)row * 2048 + col]        = h;
          o[(size_t)row * 2048 + 1024 + col] = f2bf(v - bf2f(h));
        }
      }
}

// W[e][n] f32  ->  Wt_hi/Wt_lo[n][e] bf16 split
__global__ __launch_bounds__(256)
void wt_kernel(const float* __restrict__ W, unsigned short* __restrict__ Whi,
               unsigned short* __restrict__ Wlo)
{
  __shared__ float tile[64][65];
  const int e0 = blockIdx.x * 64, n0 = blockIdx.y * 64;
  const int t = threadIdx.x;
  const int r = t >> 2, cq = t & 3;
  #pragma unroll
  for (int i = 0; i < 4; ++i){
    float4 f = *(const float4*)(W + (size_t)(e0 + r) * 1024 + n0 + cq*16 + i*4);
    tile[r][cq*16 + i*4 + 0] = f.x;
    tile[r][cq*16 + i*4 + 1] = f.y;
    tile[r][cq*16 + i*4 + 2] = f.z;
    tile[r][cq*16 + i*4 + 3] = f.w;
  }
  __syncthreads();
  unsigned short h[16], l[16];
  #pragma unroll
  for (int i = 0; i < 16; ++i){
    float v = tile[cq*16 + i][r];
    h[i] = f2bf(v);
    l[i] = f2bf(v - bf2f(h[i]));
  }
  uint4 ha, hb, la4, lb4;
  ha.x=pack2(h[0],h[1]);   ha.y=pack2(h[2],h[3]);   ha.z=pack2(h[4],h[5]);   ha.w=pack2(h[6],h[7]);
  hb.x=pack2(h[8],h[9]);   hb.y=pack2(h[10],h[11]); hb.z=pack2(h[12],h[13]); hb.w=pack2(h[14],h[15]);
  la4.x=pack2(l[0],l[1]);  la4.y=pack2(l[2],l[3]);  la4.z=pack2(l[4],l[5]);  la4.w=pack2(l[6],l[7]);
  lb4.x=pack2(l[8],l[9]);  lb4.y=pack2(l[10],l[11]);lb4.z=pack2(l[12],l[13]);lb4.w=pack2(l[14],l[15]);
  size_t o = (size_t)(n0 + r) * 1024 + e0 + cq*16;
  *(uint4*)(Whi + o)     = ha;
  *(uint4*)(Whi + o + 8) = hb;
  *(uint4*)(Wlo + o)     = la4;
  *(uint4*)(Wlo + o + 8) = lb4;
}

// k[b][kv][e] f32 -> khi/klo[b][kv][e] bf16 and kT[b][e][kv] bf16 (hi only)
__global__ __launch_bounds__(256)
void prep_kernel(const float* __restrict__ kin, unsigned short* __restrict__ khi,
                 unsigned short* __restrict__ klo, unsigned short* __restrict__ kT)
{
  __shared__ float tile[64][65];
  const int bz = blockIdx.z;
  const float* kb = kin + (size_t)bz * 2048 * 1024;
  unsigned short* khib = khi + (size_t)bz * 2048 * 1024;
  unsigned short* klob = klo + (size_t)bz * 2048 * 1024;
  unsigned short* kTb  = kT  + (size_t)bz * 1024 * 2048;
  const int kv0 = blockIdx.x * 64, e0 = blockIdx.y * 64;
  const int t = threadIdx.x;
  const int r = t >> 2, cq = t & 3;
  #pragma unroll
  for (int i = 0; i < 4; ++i){
    float4 f = *(const float4*)(kb + (size_t)(kv0 + r) * 1024 + e0 + cq*16 + i*4);
    unsigned short h0=f2bf(f.x), h1=f2bf(f.y), h2=f2bf(f.z), h3=f2bf(f.w);
    uint2 hv, lv;
    hv.x = pack2(h0, h1); hv.y = pack2(h2, h3);
    lv.x = pack2(f2bf(f.x - bf2f(h0)), f2bf(f.y - bf2f(h1)));
    lv.y = pack2(f2bf(f.z - bf2f(h2)), f2bf(f.w - bf2f(h3)));
    size_t o = (size_t)(kv0 + r) * 1024 + e0 + cq*16 + i*4;
    *(uint2*)(khib + o) = hv;
    *(uint2*)(klob + o) = lv;
    tile[r][cq*16 + i*4 + 0] = f.x;
    tile[r][cq*16 + i*4 + 1] = f.y;
    tile[r][cq*16 + i*4 + 2] = f.z;
    tile[r][cq*16 + i*4 + 3] = f.w;
  }
  __syncthreads();
  unsigned short h[16];
  #pragma unroll
  for (int i = 0; i < 16; ++i) h[i] = f2bf(tile[cq*16 + i][r]);
  uint4 va, vb;
  va.x=pack2(h[0],h[1]);  va.y=pack2(h[2],h[3]);   va.z=pack2(h[4],h[5]);   va.w=pack2(h[6],h[7]);
  vb.x=pack2(h[8],h[9]);  vb.y=pack2(h[10],h[11]); vb.z=pack2(h[12],h[13]); vb.w=pack2(h[14],h[15]);
  size_t o = (size_t)(e0 + r) * 2048 + kv0 + cq*16;
  *(uint4*)(kTb + o)     = va;
  *(uint4*)(kTb + o + 8) = vb;
}

// exact row softmax over 2048 f32, then * mask, -> bf16
__global__ __launch_bounds__(256)
void softmax_kernel(const float* __restrict__ S, const int* __restrict__ mask,
                    unsigned short* __restrict__ P)
{
  const int row = blockIdx.x;
  const float* s = S + (size_t)row * 2048;
  const int* mk = mask + (size_t)row * 2048;
  unsigned short* p = P + (size_t)row * 2048;
  const int t = threadIdx.x;
  float4 v0 = ((const float4*)s)[t];
  float4 v1 = ((const float4*)s)[t + 256];
  float m = fmaxf(fmaxf(fmaxf(v0.x, v0.y), fmaxf(v0.z, v0.w)),
                  fmaxf(fmaxf(v1.x, v1.y), fmaxf(v1.z, v1.w)));
  #pragma unroll
  for (int off = 32; off > 0; off >>= 1) m = fmaxf(m, __shfl_xor(m, off));
  __shared__ float rmax[4], rsum[4];
  const int wid = t >> 6;
  if ((t & 63) == 0) rmax[wid] = m;
  __syncthreads();
  m = fmaxf(fmaxf(rmax[0], rmax[1]), fmaxf(rmax[2], rmax[3]));
  float e0 = __expf(v0.x - m), e1 = __expf(v0.y - m), e2 = __expf(v0.z - m), e3 = __expf(v0.w - m);
  float e4 = __expf(v1.x - m), e5 = __expf(v1.y - m), e6 = __expf(v1.z - m), e7 = __expf(v1.w - m);
  float ssum = ((e0 + e1) + (e2 + e3)) + ((e4 + e5) + (e6 + e7));
  #pragma unroll
  for (int off = 32; off > 0; off >>= 1) ssum += __shfl_xor(ssum, off);
  if ((t & 63) == 0) rsum[wid] = ssum;
  __syncthreads();
  float inv = 1.f / (rsum[0] + rsum[1] + rsum[2] + rsum[3]);
  int4 m0 = ((const int4*)mk)[t];
  int4 m1 = ((const int4*)mk)[t + 256];
  ushort4 o0, o1;
  o0.x = f2bf(e0 * inv * (float)m0.x);
  o0.y = f2bf(e1 * inv * (float)m0.y);
  o0.z = f2bf(e2 * inv * (float)m0.z);
  o0.w = f2bf(e3 * inv * (float)m0.w);
  o1.x = f2bf(e4 * inv * (float)m1.x);
  o1.y = f2bf(e5 * inv * (float)m1.y);
  o1.z = f2bf(e6 * inv * (float)m1.z);
  o1.w = f2bf(e7 * inv * (float)m1.w);
  ((ushort4*)p)[t]       = o0;
  ((ushort4*)p)[t + 256] = o1;
}

extern "C" void kernel_launch(void* const* d_in, const int* in_sizes, int n_in,
                              void* d_out, int out_size, void* d_ws, size_t ws_size,
                              hipStream_t stream)
{
  (void)in_sizes; (void)n_in; (void)out_size;
  const float* kin  = (const float*)d_in[0];
  const float* qin  = (const float*)d_in[1];
  const float* Win  = (const float*)d_in[2];
  const int*   mask = (const int*)d_in[3];

  // ws layout: Wt_hi (2MB) | Wt_lo (2MB) | per-chunk { khi | klo | kT | S | P }
  unsigned short* Wt_hi = (unsigned short*)d_ws;
  unsigned short* Wt_lo = Wt_hi + 1024 * 1024;
  char* cbase = (char*)d_ws + (4ll << 20);

  int bpc = 1;  // batches per chunk (36 MB each + 4 MB fixed)
  {
    const size_t per_b = (size_t)2048*1024*2*2 + (size_t)1024*2048*2
                       + (size_t)2048*2048*4 + (size_t)2048*2048*2;
    const int cands[5] = {16, 8, 4, 2, 1};
    for (int i = 0; i < 5; ++i){
      size_t need = (4ull << 20) + (size_t)cands[i] * per_b;
      if (need <= ws_size){ bpc = cands[i]; break; }
    }
  }
  unsigned short* khi = (unsigned short*)cbase;
  unsigned short* klo = khi + (size_t)bpc * 2048 * 1024;
  unsigned short* kT  = klo + (size_t)bpc * 2048 * 1024;
  float*          Sb  = (float*)(kT + (size_t)bpc * 1024 * 2048);
  unsigned short* Pb  = (unsigned short*)(Sb + (size_t)bpc * 2048 * 2048);

  // K0: W transpose+split
  wt_kernel<<<dim3(16, 16, 1), 256, 0, stream>>>(Win, Wt_hi, Wt_lo);

  // K1: qw = q @ W  (f32-split 3-pass), -> d_out as interleaved hi|lo bf16 rows
  gemm_kernel<0, 128, 256, 8, 1><<<dim3(32768/128, 1024/256, 1), 512, 0, stream>>>(
      qin, nullptr, Wt_hi, Wt_lo, d_out,
      1024, 1024, 0, 1024, 0, 0, 0);

  for (int cb = 0; cb < 16; cb += bpc){
    prep_kernel<<<dim3(32, 16, bpc), 256, 0, stream>>>(
        kin + (size_t)cb * 2048 * 1024, khi, klo, kT);

    // K2: S = qw @ k^T (pre-split bf16 3-pass), batched
    const unsigned short* qw = (const unsigned short*)d_out + (size_t)cb * 2048 * 2048;
    gemm_kernel<1, 128, 256, 8, 0><<<dim3(2048/128, 2048/256, bpc), 512, 0, stream>>>(
        qw, qw + 1024, khi, klo, Sb,
        2048, 1024, 2048, 1024,
        (long)2048 * 2048, (long)2048 * 1024, (long)2048 * 2048);

    // K3: row softmax * mask -> P (bf16)
    softmax_kernel<<<dim3(bpc * 2048, 1, 1), 256, 0, stream>>>(
        Sb, mask + (size_t)cb * 2048 * 2048, Pb);

    // K4: O = P @ k (plain bf16), overwrites this chunk's qw rows in d_out
    gemm_kernel<2, 128, 128, 4, 0><<<dim3(2048/128, 1024/128, bpc), 256, 0, stream>>>(
        Pb, nullptr, kT, nullptr, (float*)d_out + (size_t)cb * 2048 * 1024,
        2048, 2048, 1024, 2048,
        (long)2048 * 2048, (long)1024 * 2048, (long)2048 * 1024);
  }
}